// Round 2
// baseline (16.167 us; speedup 1.0000x reference)
//
#include <hip/hip_runtime.h>

// StateStack forward on MI355X.
//
// Reference semantics:
//   new_stack = hidden_stack.at[pos+1, b].set(x)
//   out[k,b,:] = new_stack[pos[b]-1+k, b, :]   k in {0,1}
// pos+1 never collides with {pos-1, pos} at the same column b, so the scatter
// is invisible to the gather -> output reads hidden_stack directly; x/op dead.
//
// Pure memory-bound gather: 32 MB read (2KB contiguous aligned chunks) +
// 32 MB linear write. Roofline ~10 us @ 6.3 TB/s.
//
// R1: ILP=4 — 4 independent (pos, gather, store) chains per thread, strided
// by blockDim so each instruction stays unit-stride coalesced. 2048 blocks.

#define SEQ_LEN 64
#define BATCH   8192
#define HIDDEN  512
#define H4      (HIDDEN / 4)   // 128 float4 per row
#define ILP     4

__global__ __launch_bounds__(256) void StateStack_gather_kernel(
    const float4* __restrict__ stack,   // (SEQ_LEN+2, BATCH, H4) as float4
    const int*    __restrict__ pos,     // (BATCH,)
    float4*       __restrict__ out)     // (2, BATCH, H4) as float4
{
    int base = blockIdx.x * (256 * ILP) + threadIdx.x;

    int    tid[ILP];
    size_t src[ILP];
#pragma unroll
    for (int j = 0; j < ILP; ++j) {
        tid[j] = base + j * 256;
        int h4 = tid[j] & (H4 - 1);
        int bk = tid[j] >> 7;              // = b + k*BATCH
        int b  = bk & (BATCH - 1);
        int k  = bk >> 13;                 // 0 or 1
        int row = pos[b] - 1 + k;          // in [0, 64]
        src[j] = ((size_t)row * BATCH + (size_t)b) * H4 + h4;
    }

    float4 v[ILP];
#pragma unroll
    for (int j = 0; j < ILP; ++j) v[j] = stack[src[j]];
#pragma unroll
    for (int j = 0; j < ILP; ++j) out[tid[j]] = v[j];
}

extern "C" void kernel_launch(void* const* d_in, const int* in_sizes, int n_in,
                              void* d_out, int out_size, void* d_ws, size_t ws_size,
                              hipStream_t stream) {
    // inputs (setup_inputs dict order): x, hidden_stack, op, pos
    const float4* stack = (const float4*)d_in[1];
    const int*    pos   = (const int*)d_in[3];
    float4*       out   = (float4*)d_out;

    const int total4 = 2 * BATCH * H4;              // 2,097,152 float4
    const int block  = 256;
    const int grid   = total4 / (block * ILP);      // 2048 blocks
    StateStack_gather_kernel<<<grid, block, 0, stream>>>(stack, pos, out);
}